// Round 6
// baseline (216.766 us; speedup 1.0000x reference)
//
#include <hip/hip_runtime.h>
#include <hip/hip_bf16.h>

// B=2, S=2048, HID=1024, H=16, KVH=4, D=64, G=4
// qkv row stride 1536 (q:0..1023, k:1024..1279, v:1280..1535)

typedef short bfx8 __attribute__((ext_vector_type(8)));   // 8 bf16 (4 VGPRs)
typedef float fx4  __attribute__((ext_vector_type(4)));   // MFMA C/D 16x16
typedef float fx16 __attribute__((ext_vector_type(16)));  // MFMA C/D 32x32
typedef unsigned int ux4 __attribute__((ext_vector_type(4)));

#define DEV __device__ __forceinline__
#define ALPHA 0.18033688011112042f   // 1/sqrt(64) * log2(e), folded into q at GEMM1 epilogue

DEV void load_lds16(const void* g, void* l) {
  __builtin_amdgcn_global_load_lds(
      (const __attribute__((address_space(1))) unsigned int*)g,
      (__attribute__((address_space(3))) unsigned int*)l, 16, 0, 0);
}

DEV unsigned short f2bf(float f) {
  unsigned int x = __builtin_bit_cast(unsigned int, f);
  unsigned int r = (x + 0x7fffu + ((x >> 16) & 1u)) >> 16;
  return (unsigned short)r;
}
DEV float bf2f(unsigned short u) {
  unsigned int x = ((unsigned int)u) << 16;
  return __builtin_bit_cast(float, x);
}
DEV float exp2_fast(float x) { float r; asm("v_exp_f32 %0, %1" : "=v"(r) : "v"(x)); return r; }
DEV unsigned cvtpk(float lo, float hi) {
  unsigned r; asm("v_cvt_pk_bf16_f32 %0, %1, %2" : "=v"(r) : "v"(lo), "v"(hi)); return r;
}

// ---------------- x fp32 -> bf16 ----------------

__global__ __launch_bounds__(256) void cvt_x_kernel(const float* __restrict__ x,
                                                    unsigned short* __restrict__ out) {
  int i = (blockIdx.x * 256 + threadIdx.x) * 8;
  fx4 a = *(const fx4*)(x + i);
  fx4 b = *(const fx4*)(x + i + 4);
  bfx8 r;
  r[0] = (short)f2bf(a[0]); r[1] = (short)f2bf(a[1]);
  r[2] = (short)f2bf(a[2]); r[3] = (short)f2bf(a[3]);
  r[4] = (short)f2bf(b[0]); r[5] = (short)f2bf(b[1]);
  r[6] = (short)f2bf(b[2]); r[7] = (short)f2bf(b[3]);
  *(bfx8*)(out + i) = r;
}

// ---------------- fused weight transposes (f32 -> bf16), LDS-tiled ----------------
// bx<24: wqkvT rows; bx>=24: woT rows. out[r][c] = w[c][r], 64x64 tiles, stride-65 LDS.

__global__ __launch_bounds__(256) void tw_kernel(const float* __restrict__ wq,
                                                 const float* __restrict__ wk,
                                                 const float* __restrict__ wv,
                                                 const float* __restrict__ wo,
                                                 unsigned short* __restrict__ wqkvT,
                                                 unsigned short* __restrict__ woT) {
  __shared__ float tile[64 * 65];
  const int bx = blockIdx.x;
  const int c0 = blockIdx.y * 64;
  const float* src; int ncols, rofs, r0; unsigned short* dst;
  if (bx < 24) {
    r0 = bx * 64; dst = wqkvT;
    if (r0 < 1024)      { src = wq; ncols = 1024; rofs = r0; }
    else if (r0 < 1280) { src = wk; ncols = 256;  rofs = r0 - 1024; }
    else                { src = wv; ncols = 256;  rofs = r0 - 1280; }
  } else {
    r0 = (bx - 24) * 64; dst = woT; src = wo; ncols = 1024; rofs = r0;
  }
  const int t = threadIdx.x;
#pragma unroll
  for (int p = 0; p < 4; ++p) {
    int idx = p * 256 + t;
    int cc = idx >> 4, q4 = idx & 15;
    fx4 v = *(const fx4*)(src + (size_t)(c0 + cc) * ncols + rofs + q4 * 4);
#pragma unroll
    for (int i = 0; i < 4; ++i) tile[(q4 * 4 + i) * 65 + cc] = v[i];
  }
  __syncthreads();
#pragma unroll
  for (int p = 0; p < 2; ++p) {
    int idx = p * 256 + t;
    int rr = idx >> 3, c8 = idx & 7;
    bfx8 v8;
#pragma unroll
    for (int i = 0; i < 8; ++i) v8[i] = (short)f2bf(tile[rr * 65 + c8 * 8 + i]);
    *(bfx8*)(dst + (size_t)(r0 + rr) * 1024 + c0 + c8 * 8) = v8;
  }
}

// ---------------- V^T pre-pass: vT[b][kvh][d=64][s=2048] ----------------

__global__ __launch_bounds__(256) void vt_kernel(const unsigned short* __restrict__ qkv,
                                                 unsigned short* __restrict__ vT) {
  __shared__ __align__(16) unsigned short tile[64][72];
  const int sc = blockIdx.x;            // s-chunk 0..31
  const int kvh = blockIdx.y, b = blockIdx.z;
  const int t = threadIdx.x;
  const unsigned short* src = qkv + ((size_t)b * 2048 + sc * 64) * 1536 + 1280 + kvh * 64;
#pragma unroll
  for (int p = 0; p < 2; ++p) {
    int idx = p * 256 + t;
    int row = idx >> 3, c = idx & 7;
    *(bfx8*)(&tile[row][c * 8]) = *(const bfx8*)(src + (size_t)row * 1536 + c * 8);
  }
  __syncthreads();
  unsigned short* dst = vT + ((size_t)(b * 4 + kvh) * 64) * 2048 + sc * 64;
#pragma unroll
  for (int p = 0; p < 2; ++p) {
    int idx = p * 256 + t;
    int d = idx >> 3, c = idx & 7;
    bfx8 v;
#pragma unroll
    for (int i = 0; i < 8; ++i) v[i] = (short)tile[c * 8 + i][d];
    *(bfx8*)(dst + (size_t)d * 2048 + c * 8) = v;
  }
}

// ---------------- GEMM: C[M][ldc] = A[M][K] * Bt[N][K]^T (optional fused RoPE) ----------------

template <bool OUT_BF16, bool FUSE_ROPE>
__global__ __launch_bounds__(256) void gemm_bt_kernel(const unsigned short* __restrict__ A,
                                                      const unsigned short* __restrict__ Bt,
                                                      void* __restrict__ Cp,
                                                      int M, int N, int K, int ldc,
                                                      const float* __restrict__ ct,
                                                      const float* __restrict__ st) {
  __shared__ __align__(16) unsigned short As[128 * 32];
  __shared__ __align__(16) unsigned short Bs[128 * 32];
  const int t = threadIdx.x;
  const int l = t & 63;
  const int w = t >> 6;
  const int wm = (w >> 1) * 64, wn = (w & 1) * 64;
  const int bm = blockIdx.x, bn = blockIdx.y;
  fx4 acc[4][4] = {};

  const int ra = t >> 2;
  const int ca = t & 3;

  for (int kt = 0; kt < K; kt += 32) {
    __syncthreads();
#pragma unroll
    for (int p = 0; p < 2; ++p) {
      int rr = ra + p * 64;
      int gca = ((ca ^ ((rr >> 1) & 3)) * 8);
      load_lds16(A + (size_t)(bm * 128 + rr) * K + kt + gca, (char*)As + p * 4096 + t * 16);
      load_lds16(Bt + (size_t)(bn * 128 + rr) * K + kt + gca, (char*)Bs + p * 4096 + t * 16);
    }
    __syncthreads();

    bfx8 af[4], bfr[4];
#pragma unroll
    for (int mi = 0; mi < 4; ++mi) {
      int row = wm + mi * 16 + (l & 15);
      int ch = (l >> 4) ^ ((row >> 1) & 3);
      af[mi] = *(const bfx8*)(As + row * 32 + ch * 8);
      int rowb = wn + mi * 16 + (l & 15);
      int chb = (l >> 4) ^ ((rowb >> 1) & 3);
      bfr[mi] = *(const bfx8*)(Bs + rowb * 32 + chb * 8);
    }
#pragma unroll
    for (int mi = 0; mi < 4; ++mi)
#pragma unroll
      for (int ni = 0; ni < 4; ++ni)
        acc[mi][ni] = __builtin_amdgcn_mfma_f32_16x16x32_bf16(af[mi], bfr[ni], acc[mi][ni], 0, 0, 0);
  }

  const int colbase = bn * 128 + wn;              // head-aligned 64-col window
  if (FUSE_ROPE && colbase < 1280) {
    const float qsc = (colbase < 1024) ? ALPHA : 1.0f;
    unsigned short* Cb = (unsigned short*)Cp;
#pragma unroll
    for (int mi = 0; mi < 4; ++mi) {
      int row0 = bm * 128 + wm + mi * 16 + (l >> 4) * 4;
#pragma unroll
      for (int r = 0; r < 4; ++r) {
        int row = row0 + r, s = row & 2047;
#pragma unroll
        for (int ni = 0; ni < 2; ++ni) {
          int d = ni * 16 + (l & 15);
          float c = ct[s * 64 + d], sn = st[s * 64 + d];
          float x0 = acc[mi][ni][r], x1 = acc[mi][ni + 2][r];
          Cb[(size_t)row * ldc + colbase + d]      = f2bf((x0 * c - x1 * sn) * qsc);
          Cb[(size_t)row * ldc + colbase + d + 32] = f2bf((x1 * c + x0 * sn) * qsc);
        }
      }
    }
  } else {
#pragma unroll
    for (int mi = 0; mi < 4; ++mi) {
      int row0 = bm * 128 + wm + mi * 16 + (l >> 4) * 4;
#pragma unroll
      for (int ni = 0; ni < 4; ++ni) {
        int col = colbase + ni * 16 + (l & 15);
#pragma unroll
        for (int r = 0; r < 4; ++r) {
          if (OUT_BF16)
            ((unsigned short*)Cp)[(size_t)(row0 + r) * ldc + col] = f2bf(acc[mi][ni][r]);
          else
            ((float*)Cp)[(size_t)(row0 + r) * ldc + col] = acc[mi][ni][r];
        }
      }
    }
  }
}

// ---------------- flash attention: paired tiles + 2-way split-KV + triple prefetch ----------------
// 1024 blocks x 128 threads (2 waves). Block handles q-tiles t0=pid and t1=63-pid
// (65 KV steps total). Wave w does KV steps kb ≡ w (mod 2) with private (m,l,o);
// per-tile 2-way LDS merge. Swapped QK^T (S^T=K*Q) + swapped PV (O^T=V^T*P^T):
// lane's q = l&31 everywhere. K/V^T frags gathered from global (L2-resident);
// fA/fB/fC register triple-buffer = 2-step lookahead.

struct Frag { bfx8 kf[4]; bfx8 vf[4]; };

__global__ __launch_bounds__(128) void attn_kernel(const unsigned short* __restrict__ qkv,
                                                   const unsigned short* __restrict__ vT,
                                                   unsigned short* __restrict__ out) {
  __shared__ float OX[2][16][64];       // o-exchange: [dt][r][lane]  (8 KB)
  __shared__ unsigned Ost[32 * 33];     // transpose buffer            (4.2 KB)
  __shared__ float Msh[2 * 64], Lsh[2 * 64];
  const int fid = blockIdx.x;
  const int pid = fid & 31;
  const int uu = fid >> 5;
  const int head = uu & 15, b = uu >> 4;
  const int kvh = head >> 2;
  const int t = threadIdx.x, w = t >> 6, l = t & 63;
  const int q5 = l & 31, h = l >> 5;
  const size_t bbase = (size_t)b * 2048;
  const unsigned short* base = qkv + bbase * 1536;
  const unsigned short* kptr = base + 1024 + kvh * 64 + (size_t)q5 * 1536 + 8 * h;
  const unsigned short* vptr = vT + ((size_t)(b * 4 + kvh) * 64 + q5) * 2048 + 8 * h;

  Frag fA, fB, fC;

#define LOADF(F, KB) do {                                                        \
    const unsigned short* kq = kptr + (size_t)(KB) * (32 * 1536);                \
    F.kf[0] = *(const bfx8*)(kq);                                                \
    F.kf[1] = *(const bfx8*)(kq + 16);                                           \
    F.kf[2] = *(const bfx8*)(kq + 32);                                           \
    F.kf[3] = *(const bfx8*)(kq + 48);                                           \
    const unsigned short* vq = vptr + (KB) * 32;                                 \
    F.vf[0] = *(const bfx8*)(vq);                                                \
    F.vf[1] = *(const bfx8*)(vq + 32 * 2048);                                    \
    F.vf[2] = *(const bfx8*)(vq + 16);                                           \
    F.vf[3] = *(const bfx8*)(vq + 16 + 32 * 2048);                               \
  } while (0)

#define STEP(F, KB) do {                                                         \
    fx16 s = {};                                                                 \
    s = __builtin_amdgcn_mfma_f32_32x32x16_bf16(F.kf[0], qf[0], s, 0, 0, 0);     \
    s = __builtin_amdgcn_mfma_f32_32x32x16_bf16(F.kf[1], qf[1], s, 0, 0, 0);     \
    s = __builtin_amdgcn_mfma_f32_32x32x16_bf16(F.kf[2], qf[2], s, 0, 0, 0);     \
    s = __builtin_amdgcn_mfma_f32_32x32x16_bf16(F.kf[3], qf[3], s, 0, 0, 0);     \
    if ((KB) == Tp) {                                                            \
      _Pragma("unroll")                                                          \
      for (int r = 0; r < 16; ++r) {                                             \
        int kr = (r & 3) + 8 * (r >> 2) + 4 * h;                                 \
        if (kr > q5) s[r] = -1e30f;                                              \
      }                                                                          \
    }                                                                            \
    float pmax = s[0];                                                           \
    _Pragma("unroll")                                                            \
    for (int r = 1; r < 16; ++r) pmax = fmaxf(pmax, s[r]);                       \
    pmax = fmaxf(pmax, __shfl_xor(pmax, 32, 64));                                \
    if (!__all(pmax <= mrun + 8.0f)) {                                           \
      float mnew = fmaxf(mrun, pmax);                                            \
      float corr = exp2_fast(mrun - mnew);                                       \
      mrun = mnew;                                                               \
      lrun *= corr;                                                              \
      o[0] *= corr; o[1] *= corr;                                                \
    }                                                                            \
    float lt = 0.f;                                                              \
    _Pragma("unroll")                                                            \
    for (int r = 0; r < 16; ++r) { float pv = exp2_fast(s[r] - mrun); s[r] = pv; lt += pv; } \
    lt += __shfl_xor(lt, 32, 64);                                                \
    lrun += lt;                                                                  \
    unsigned U[8];                                                               \
    _Pragma("unroll")                                                            \
    for (int k8 = 0; k8 < 8; ++k8) U[k8] = cvtpk(s[2 * k8], s[2 * k8 + 1]);      \
    _Pragma("unroll")                                                            \
    for (int kc = 0; kc < 2; ++kc) {                                             \
      unsigned send0 = h ? U[4 * kc] : U[4 * kc + 2];                            \
      unsigned send1 = h ? U[4 * kc + 1] : U[4 * kc + 3];                        \
      unsigned r0 = (unsigned)__shfl_xor((int)send0, 32, 64);                    \
      unsigned r1 = (unsigned)__shfl_xor((int)send1, 32, 64);                    \
      unsigned k0 = h ? U[4 * kc + 2] : U[4 * kc];                               \
      unsigned k1 = h ? U[4 * kc + 3] : U[4 * kc + 1];                           \
      ux4 fr;                                                                    \
      fr[0] = h ? r0 : k0; fr[1] = h ? r1 : k1;                                  \
      fr[2] = h ? k0 : r0; fr[3] = h ? k1 : r1;                                  \
      bfx8 pf = __builtin_bit_cast(bfx8, fr);                                    \
      o[0] = __builtin_amdgcn_mfma_f32_32x32x16_bf16(F.vf[kc * 2], pf, o[0], 0, 0, 0);     \
      o[1] = __builtin_amdgcn_mfma_f32_32x32x16_bf16(F.vf[kc * 2 + 1], pf, o[1], 0, 0, 0); \
    }                                                                            \
  } while (0)

#pragma unroll 1
  for (int sel = 0; sel < 2; ++sel) {
    const int Tp = sel ? (63 - pid) : pid;
    const int q0 = Tp * 32;
    const int nkb = Tp + 1;

    bfx8 qf[4];
#pragma unroll
    for (int dd = 0; dd < 4; ++dd)
      qf[dd] = *(const bfx8*)(base + (size_t)(q0 + q5) * 1536 + head * 64 + dd * 16 + 8 * h);

    fx16 o[2] = {};
    float mrun = -1e30f, lrun = 0.f;

    // wave w handles kb = w, w+2, w+4, ...  (triple-buffer: 2-step lookahead)
    int kb = w;
    if (kb < nkb) {
      LOADF(fA, kb);
      if (kb + 2 < nkb) LOADF(fB, kb + 2);
      while (true) {
        if (kb + 4 < nkb) LOADF(fC, kb + 4);
        STEP(fA, kb);
        kb += 2; if (kb >= nkb) break;
        if (kb + 4 < nkb) LOADF(fA, kb + 4);
        STEP(fB, kb);
        kb += 2; if (kb >= nkb) break;
        if (kb + 4 < nkb) LOADF(fB, kb + 4);
        STEP(fC, kb);
        kb += 2; if (kb >= nkb) break;
      }
    }

    // ---- 2-way merge ----
    Msh[w * 64 + l] = mrun;
    __syncthreads();
    float mtot = fmaxf(Msh[l], Msh[64 + l]);
    float sc = exp2_fast(mrun - mtot);
    Lsh[w * 64 + l] = lrun * sc;
    o[0] *= sc; o[1] *= sc;
    // wave w exports its other-half (dt = 1-w)
    {
      fx16 oth = w ? o[0] : o[1];
      int dto = 1 - w;
#pragma unroll
      for (int r = 0; r < 16; ++r) OX[dto][r][l] = oth[r];
    }
    __syncthreads();
    float ltot = Lsh[l] + Lsh[64 + l];
    float inv = 1.0f / ltot;
    fx16 mine = w ? o[1] : o[0];
#pragma unroll
    for (int r = 0; r < 16; ++r) mine[r] = (mine[r] + OX[w][r][l]) * inv;

    // ---- transpose to Ost (wave w owns d in [32w, 32w+32)) ----
#pragma unroll
    for (int rp = 0; rp < 8; ++rp) {
      int r = 2 * rp;
      int d = 32 * w + (r & 3) + 8 * (r >> 2) + 4 * h;   // even d; pair (d, d+1)
      Ost[q5 * 33 + (d >> 1)] = cvtpk(mine[r], mine[r + 1]);
    }
    __syncthreads();
    // ---- cooperative coalesced store: 128 threads, q = t>>2, 16 bf16 each x2 ----
    {
      int q = t >> 2, c = t & 3;
      const unsigned* src = Ost + q * 33 + c * 8;
      unsigned short* dst = out + (bbase + q0 + q) * 1024 + head * 64 + c * 16;
      ux4 v0, v1;
      v0[0] = src[0]; v0[1] = src[1]; v0[2] = src[2]; v0[3] = src[3];
      v1[0] = src[4]; v1[1] = src[5]; v1[2] = src[6]; v1[3] = src[7];
      *(ux4*)(dst) = v0;
      *(ux4*)(dst + 8) = v1;
    }
    __syncthreads();   // Ost/OX reused next sel
  }
#undef LOADF
#undef STEP
}

// ---------------- launch ----------------

extern "C" void kernel_launch(void* const* d_in, const int* in_sizes, int n_in,
                              void* d_out, int out_size, void* d_ws, size_t ws_size,
                              hipStream_t stream) {
  const float* x    = (const float*)d_in[0];
  const float* cosb = (const float*)d_in[1];
  const float* sinb = (const float*)d_in[2];
  const float* wq   = (const float*)d_in[3];
  const float* wk   = (const float*)d_in[4];
  const float* wv   = (const float*)d_in[5];
  const float* wo   = (const float*)d_in[6];
  float* out = (float*)d_out;

  char* ws = (char*)d_ws;
  unsigned short* xb    = (unsigned short*)ws;                 //  8,388,608 B
  unsigned short* attn  = (unsigned short*)ws;                 //  (alias; xb dead by then)
  unsigned short* wqkvT = (unsigned short*)(ws + 8388608);     //  3,145,728 B
  unsigned short* vT    = (unsigned short*)(ws + 8388608);     //  (alias; wqkvT dead after gemm1)
  unsigned short* woT   = (unsigned short*)(ws + 11534336);    //  2,097,152 B
  unsigned short* qkv   = (unsigned short*)(ws + 13631488);    // 12,582,912 B

  cvt_x_kernel<<<2048, 256, 0, stream>>>(x, xb);
  tw_kernel<<<dim3(40, 16), 256, 0, stream>>>(wq, wk, wv, wo, wqkvT, woT);
  gemm_bt_kernel<true, true><<<dim3(32, 12), 256, 0, stream>>>(xb, wqkvT, qkv, 4096, 1536, 1024, 1536, cosb, sinb);
  vt_kernel<<<dim3(32, 4, 2), 256, 0, stream>>>(qkv, vT);
  attn_kernel<<<1024, 128, 0, stream>>>(qkv, vT, attn);
  gemm_bt_kernel<false, false><<<dim3(32, 8), 256, 0, stream>>>(attn, woT, out, 4096, 1024, 1024, 1024, nullptr, nullptr);
}

// Round 7
// 203.644 us; speedup vs baseline: 1.0644x; 1.0644x over previous
//
#include <hip/hip_runtime.h>
#include <hip/hip_bf16.h>

// B=2, S=2048, HID=1024, H=16, KVH=4, D=64, G=4
// qkv row stride 1280 (q:0..1023, k:1024..1279); v goes straight to vT[b][kvh][64][2048]

typedef short bfx4 __attribute__((ext_vector_type(4)));
typedef short bfx8 __attribute__((ext_vector_type(8)));   // 8 bf16 (4 VGPRs)
typedef float fx4  __attribute__((ext_vector_type(4)));   // MFMA C/D 16x16
typedef float fx16 __attribute__((ext_vector_type(16)));  // MFMA C/D 32x32
typedef unsigned int ux4 __attribute__((ext_vector_type(4)));

#define DEV __device__ __forceinline__
#define ALPHA 0.18033688011112042f   // 1/sqrt(64) * log2(e), folded into q at GEMM1 epilogue

DEV void load_lds16(const void* g, void* l) {
  __builtin_amdgcn_global_load_lds(
      (const __attribute__((address_space(1))) unsigned int*)g,
      (__attribute__((address_space(3))) unsigned int*)l, 16, 0, 0);
}

DEV unsigned short f2bf(float f) {
  unsigned int x = __builtin_bit_cast(unsigned int, f);
  unsigned int r = (x + 0x7fffu + ((x >> 16) & 1u)) >> 16;
  return (unsigned short)r;
}
DEV float exp2_fast(float x) { float r; asm("v_exp_f32 %0, %1" : "=v"(r) : "v"(x)); return r; }
DEV unsigned cvtpk(float lo, float hi) {
  unsigned r; asm("v_cvt_pk_bf16_f32 %0, %1, %2" : "=v"(r) : "v"(lo), "v"(hi)); return r;
}
#define MFMA32 __builtin_amdgcn_mfma_f32_32x32x16_bf16

// ---------------- x fp32 -> bf16 ----------------

__global__ __launch_bounds__(256) void cvt_x_kernel(const float* __restrict__ x,
                                                    unsigned short* __restrict__ out) {
  int i = (blockIdx.x * 256 + threadIdx.x) * 8;
  fx4 a = *(const fx4*)(x + i);
  fx4 b = *(const fx4*)(x + i + 4);
  bfx8 r;
  r[0] = (short)f2bf(a[0]); r[1] = (short)f2bf(a[1]);
  r[2] = (short)f2bf(a[2]); r[3] = (short)f2bf(a[3]);
  r[4] = (short)f2bf(b[0]); r[5] = (short)f2bf(b[1]);
  r[6] = (short)f2bf(b[2]); r[7] = (short)f2bf(b[3]);
  *(bfx8*)(out + i) = r;
}

// ---------------- fused weight transposes (f32 -> bf16), LDS-tiled ----------------

__global__ __launch_bounds__(256) void tw_kernel(const float* __restrict__ wq,
                                                 const float* __restrict__ wk,
                                                 const float* __restrict__ wv,
                                                 const float* __restrict__ wo,
                                                 unsigned short* __restrict__ wqkvT,
                                                 unsigned short* __restrict__ woT) {
  __shared__ float tile[64 * 65];
  const int bx = blockIdx.x;
  const int c0 = blockIdx.y * 64;
  const float* src; int ncols, rofs, r0; unsigned short* dst;
  if (bx < 24) {
    r0 = bx * 64; dst = wqkvT;
    if (r0 < 1024)      { src = wq; ncols = 1024; rofs = r0; }
    else if (r0 < 1280) { src = wk; ncols = 256;  rofs = r0 - 1024; }
    else                { src = wv; ncols = 256;  rofs = r0 - 1280; }
  } else {
    r0 = (bx - 24) * 64; dst = woT; src = wo; ncols = 1024; rofs = r0;
  }
  const int t = threadIdx.x;
#pragma unroll
  for (int p = 0; p < 4; ++p) {
    int idx = p * 256 + t;
    int cc = idx >> 4, q4 = idx & 15;
    fx4 v = *(const fx4*)(src + (size_t)(c0 + cc) * ncols + rofs + q4 * 4);
#pragma unroll
    for (int i = 0; i < 4; ++i) tile[(q4 * 4 + i) * 65 + cc] = v[i];
  }
  __syncthreads();
#pragma unroll
  for (int p = 0; p < 2; ++p) {
    int idx = p * 256 + t;
    int rr = idx >> 3, c8 = idx & 7;
    bfx8 v8;
#pragma unroll
    for (int i = 0; i < 8; ++i) v8[i] = (short)f2bf(tile[rr * 65 + c8 * 8 + i]);
    *(bfx8*)(dst + (size_t)(r0 + rr) * 1024 + c0 + c8 * 8) = v8;
  }
}

// ---------------- GEMM 64x128 tile: C[M][ldc] = A[M][K] * Bt[N][K]^T ----------------
// 4 waves of 32x64; FUSE_ROPE: cols<1280 -> rope -> qkv (ld 1280); cols>=1280 -> vT (transposed).

template <bool OUT_BF16, bool FUSE_ROPE>
__global__ __launch_bounds__(256) void gemm_bt_kernel(const unsigned short* __restrict__ A,
                                                      const unsigned short* __restrict__ Bt,
                                                      void* __restrict__ Cp,
                                                      int K, int ldc,
                                                      const float* __restrict__ ct,
                                                      const float* __restrict__ st,
                                                      unsigned short* __restrict__ vTout) {
  __shared__ __align__(16) unsigned short As[64 * 32];
  __shared__ __align__(16) unsigned short Bs[128 * 32];
  const int t = threadIdx.x;
  const int l = t & 63;
  const int w = t >> 6;
  const int wm = (w >> 1) * 32, wn = (w & 1) * 64;
  const int bm = blockIdx.x, bn = blockIdx.y;
  fx4 acc[2][4] = {};

  for (int kt = 0; kt < K; kt += 32) {
    __syncthreads();
    {
      int rr = t >> 2, ca = t & 3;
      int gca = ((ca ^ ((rr >> 1) & 3)) * 8);
      load_lds16(A + (size_t)(bm * 64 + rr) * K + kt + gca, (char*)As + t * 16);
    }
#pragma unroll
    for (int p = 0; p < 2; ++p) {
      int idx = p * 256 + t;
      int rr = idx >> 2, ca = idx & 3;
      int gca = ((ca ^ ((rr >> 1) & 3)) * 8);
      load_lds16(Bt + (size_t)(bn * 128 + rr) * K + kt + gca, (char*)Bs + idx * 16);
    }
    __syncthreads();

    bfx8 af[2], bfr[4];
#pragma unroll
    for (int mi = 0; mi < 2; ++mi) {
      int row = wm + mi * 16 + (l & 15);
      int ch = (l >> 4) ^ ((row >> 1) & 3);
      af[mi] = *(const bfx8*)(As + row * 32 + ch * 8);
    }
#pragma unroll
    for (int ni = 0; ni < 4; ++ni) {
      int rowb = wn + ni * 16 + (l & 15);
      int chb = (l >> 4) ^ ((rowb >> 1) & 3);
      bfr[ni] = *(const bfx8*)(Bs + rowb * 32 + chb * 8);
    }
#pragma unroll
    for (int mi = 0; mi < 2; ++mi)
#pragma unroll
      for (int ni = 0; ni < 4; ++ni)
        acc[mi][ni] = __builtin_amdgcn_mfma_f32_16x16x32_bf16(af[mi], bfr[ni], acc[mi][ni], 0, 0, 0);
  }

  const int colbase = bn * 128 + wn;              // head-aligned 64-col window
  if (FUSE_ROPE && colbase < 1280) {
    const float qsc = (colbase < 1024) ? ALPHA : 1.0f;
    unsigned short* Cb = (unsigned short*)Cp;
#pragma unroll
    for (int mi = 0; mi < 2; ++mi) {
      int row0 = bm * 64 + wm + mi * 16 + (l >> 4) * 4;
#pragma unroll
      for (int r = 0; r < 4; ++r) {
        int row = row0 + r, s = row & 2047;
#pragma unroll
        for (int ni = 0; ni < 2; ++ni) {
          int d = ni * 16 + (l & 15);
          float c = ct[s * 64 + d], sn = st[s * 64 + d];
          float x0 = acc[mi][ni][r], x1 = acc[mi][ni + 2][r];
          Cb[(size_t)row * 1280 + colbase + d]      = f2bf((x0 * c - x1 * sn) * qsc);
          Cb[(size_t)row * 1280 + colbase + d + 32] = f2bf((x1 * c + x0 * sn) * qsc);
        }
      }
    }
  } else if (FUSE_ROPE) {
    // v-part: write transposed to vT[(b*4+kvh)*64 + d][s], 8B packs (4 consecutive s)
    const int b4 = (bm >> 5) * 4;                 // b = bm*64 / 2048
#pragma unroll
    for (int mi = 0; mi < 2; ++mi) {
      int row0 = bm * 64 + wm + mi * 16 + (l >> 4) * 4;
      int s0r = row0 & 2047;
#pragma unroll
      for (int ni = 0; ni < 4; ++ni) {
        int vcol = colbase + ni * 16 + (l & 15) - 1280;
        int kvh = vcol >> 6, d = vcol & 63;
        bfx4 pv;
#pragma unroll
        for (int r = 0; r < 4; ++r) pv[r] = (short)f2bf(acc[mi][ni][r]);
        *(bfx4*)(vTout + ((size_t)(b4 + kvh) * 64 + d) * 2048 + s0r) = pv;
      }
    }
  } else {
#pragma unroll
    for (int mi = 0; mi < 2; ++mi) {
      int row0 = bm * 64 + wm + mi * 16 + (l >> 4) * 4;
#pragma unroll
      for (int ni = 0; ni < 4; ++ni) {
        int col = colbase + ni * 16 + (l & 15);
#pragma unroll
        for (int r = 0; r < 4; ++r) {
          if (OUT_BF16)
            ((unsigned short*)Cp)[(size_t)(row0 + r) * ldc + col] = f2bf(acc[mi][ni][r]);
          else
            ((float*)Cp)[(size_t)(row0 + r) * ldc + col] = acc[mi][ni][r];
        }
      }
    }
  }
}

// ---------------- flash attention v7: 1 wave/block, KVBLK=64, dual-chain softmax ----------------
// 2048 blocks x 64 thr, sorted descending by work: Tp = 63-(fid>>5), (head,b) = fid&31.
// Swapped QK^T (S^T=K*Q) + swapped PV (O^T=V^T*P^T): lane's q = l&31 everywhere.
// K reg-double-buffered; V loaded at step start, consumed after softmax (T14).
// No barriers; epilogue transpose via wave-local LDS + lgkmcnt(0).

__global__ __launch_bounds__(64, 2) void attn_kernel(const unsigned short* __restrict__ qkv,
                                                     const unsigned short* __restrict__ vT,
                                                     unsigned short* __restrict__ out) {
  __shared__ unsigned Ost[32 * 33];
  const int fid = blockIdx.x;
  const int Tp = 63 - (fid >> 5);
  const int hb = fid & 31;
  const int head = hb & 15, b = hb >> 4;
  const int kvh = head >> 2;
  const int l = threadIdx.x, q5 = l & 31, h = l >> 5;
  const int q0 = Tp * 32;
  const int nkb = (Tp >> 1) + 1;
  const size_t bbase = (size_t)b * 2048;
  const unsigned short* base = qkv + bbase * 1280;
  const unsigned short* kptr = base + 1024 + kvh * 64 + (size_t)q5 * 1280 + 8 * h;
  const unsigned short* vptr = vT + ((size_t)(b * 4 + kvh) * 64 + q5) * 2048 + 8 * h;

  bfx8 qf[4];
#pragma unroll
  for (int dd = 0; dd < 4; ++dd)
    qf[dd] = *(const bfx8*)(base + (size_t)(q0 + q5) * 1280 + head * 64 + dd * 16 + 8 * h);

  fx16 o[2] = {};
  float mrun = -1e30f, lrun = 0.f;
  bfx8 kfA[8], kfB[8], va[8];

#define LOADK(KF, KB) do {                                                       \
    const unsigned short* kq = kptr + (size_t)((KB) * 64) * 1280;                \
    KF[0] = *(const bfx8*)(kq);                                                  \
    KF[1] = *(const bfx8*)(kq + 16);                                             \
    KF[2] = *(const bfx8*)(kq + 32);                                             \
    KF[3] = *(const bfx8*)(kq + 48);                                             \
    const unsigned short* kq1 = kq + 32 * 1280;                                  \
    KF[4] = *(const bfx8*)(kq1);                                                 \
    KF[5] = *(const bfx8*)(kq1 + 16);                                            \
    KF[6] = *(const bfx8*)(kq1 + 32);                                            \
    KF[7] = *(const bfx8*)(kq1 + 48);                                            \
  } while (0)

#define LOADV(KB) do {                                                           \
    const unsigned short* vq = vptr + (KB) * 64;                                 \
    va[0] = *(const bfx8*)(vq);                                                  \
    va[1] = *(const bfx8*)(vq + 16);                                             \
    va[2] = *(const bfx8*)(vq + 32);                                             \
    va[3] = *(const bfx8*)(vq + 48);                                             \
    const unsigned short* vq1 = vq + 32 * 2048;                                  \
    va[4] = *(const bfx8*)(vq1);                                                 \
    va[5] = *(const bfx8*)(vq1 + 16);                                            \
    va[6] = *(const bfx8*)(vq1 + 32);                                            \
    va[7] = *(const bfx8*)(vq1 + 48);                                            \
  } while (0)

#define STEP(KF, KB) do {                                                        \
    fx16 s0 = {}, s1 = {};                                                       \
    __builtin_amdgcn_s_setprio(1);                                               \
    s0 = MFMA32(KF[0], qf[0], s0, 0, 0, 0);                                      \
    s1 = MFMA32(KF[4], qf[0], s1, 0, 0, 0);                                      \
    s0 = MFMA32(KF[1], qf[1], s0, 0, 0, 0);                                      \
    s1 = MFMA32(KF[5], qf[1], s1, 0, 0, 0);                                      \
    s0 = MFMA32(KF[2], qf[2], s0, 0, 0, 0);                                      \
    s1 = MFMA32(KF[6], qf[2], s1, 0, 0, 0);                                      \
    s0 = MFMA32(KF[3], qf[3], s0, 0, 0, 0);                                      \
    s1 = MFMA32(KF[7], qf[3], s1, 0, 0, 0);                                      \
    __builtin_amdgcn_s_setprio(0);                                               \
    if ((KB) == nkb - 1) {                                                       \
      const int j0s = (KB) * 64;                                                 \
      _Pragma("unroll")                                                          \
      for (int r = 0; r < 16; ++r) {                                             \
        int key0 = j0s + (r & 3) + 8 * (r >> 2) + 4 * h;                         \
        if (key0 > q0 + q5) s0[r] = -1e30f;                                      \
        if (key0 + 32 > q0 + q5) s1[r] = -1e30f;                                 \
      }                                                                          \
    }                                                                            \
    float pmax = fmaxf(s0[0], s1[0]);                                            \
    _Pragma("unroll")                                                            \
    for (int r = 1; r < 16; ++r) pmax = fmaxf(pmax, fmaxf(s0[r], s1[r]));        \
    pmax = fmaxf(pmax, __shfl_xor(pmax, 32, 64));                                \
    if (!__all(pmax <= mrun + 8.0f)) {                                           \
      float mnew = fmaxf(mrun, pmax);                                            \
      float corr = exp2_fast(mrun - mnew);                                       \
      mrun = mnew;                                                               \
      lrun *= corr;                                                              \
      o[0] *= corr; o[1] *= corr;                                                \
    }                                                                            \
    float lt0 = 0.f, lt1 = 0.f;                                                  \
    _Pragma("unroll")                                                            \
    for (int r = 0; r < 16; ++r) {                                               \
      float p0 = exp2_fast(s0[r] - mrun); s0[r] = p0; lt0 += p0;                 \
      float p1 = exp2_fast(s1[r] - mrun); s1[r] = p1; lt1 += p1;                 \
    }                                                                            \
    float lt = lt0 + lt1;                                                        \
    lt += __shfl_xor(lt, 32, 64);                                                \
    lrun += lt;                                                                  \
    unsigned U[2][8];                                                            \
    _Pragma("unroll")                                                            \
    for (int k8 = 0; k8 < 8; ++k8) {                                             \
      U[0][k8] = cvtpk(s0[2 * k8], s0[2 * k8 + 1]);                              \
      U[1][k8] = cvtpk(s1[2 * k8], s1[2 * k8 + 1]);                              \
    }                                                                            \
    _Pragma("unroll")                                                            \
    for (int hs = 0; hs < 2; ++hs) {                                             \
      _Pragma("unroll")                                                          \
      for (int e = 0; e < 2; ++e) {                                              \
        unsigned send0 = h ? U[hs][4 * e] : U[hs][4 * e + 2];                    \
        unsigned send1 = h ? U[hs][4 * e + 1] : U[hs][4 * e + 3];                \
        unsigned r0 = (unsigned)__shfl_xor((int)send0, 32, 64);                  \
        unsigned r1 = (unsigned)__shfl_xor((int)send1, 32, 64);                  \
        unsigned k0 = h ? U[hs][4 * e + 2] : U[hs][4 * e];                       \
        unsigned k1 = h ? U[hs][4 * e + 3] : U[hs][4 * e + 1];                   \
        ux4 fr;                                                                  \
        fr[0] = h ? r0 : k0; fr[1] = h ? r1 : k1;                                \
        fr[2] = h ? k0 : r0; fr[3] = h ? k1 : r1;                                \
        bfx8 pf = __builtin_bit_cast(bfx8, fr);                                  \
        __builtin_amdgcn_s_setprio(1);                                           \
        o[0] = MFMA32(va[2 * hs + e], pf, o[0], 0, 0, 0);                        \
        o[1] = MFMA32(va[4 + 2 * hs + e], pf, o[1], 0, 0, 0);                    \
        __builtin_amdgcn_s_setprio(0);                                           \
      }                                                                          \
    }                                                                            \
  } while (0)

  LOADK(kfA, 0);
  int kb = 0;
  while (true) {
    LOADV(kb);
    if (kb + 1 < nkb) LOADK(kfB, kb + 1);
    STEP(kfA, kb);
    ++kb; if (kb >= nkb) break;
    LOADV(kb);
    if (kb + 1 < nkb) LOADK(kfA, kb + 1);
    STEP(kfB, kb);
    ++kb; if (kb >= nkb) break;
  }
#undef LOADK
#undef LOADV
#undef STEP

  // ---- epilogue: O^T -> wave-local LDS transpose -> coalesced bf16 store ----
  float inv = 1.0f / lrun;
#pragma unroll
  for (int dt = 0; dt < 2; ++dt)
#pragma unroll
    for (int rp = 0; rp < 8; ++rp) {
      int r = 2 * rp;
      int d = 32 * dt + (r & 3) + 8 * (r >> 2) + 4 * h;   // even d; pair (d, d+1)
      Ost[q5 * 33 + (d >> 1)] = cvtpk(o[dt][r] * inv, o[dt][r + 1] * inv);
    }
  asm volatile("s_waitcnt lgkmcnt(0)" ::: "memory");
  __builtin_amdgcn_sched_barrier(0);
  {
    int rr = l >> 1, half = l & 1;
    const unsigned* src = Ost + rr * 33 + half * 16;
    unsigned short* dst = out + (bbase + q0 + rr) * 1024 + head * 64 + half * 32;
#pragma unroll
    for (int u2 = 0; u2 < 4; ++u2) {
      ux4 v4;
      v4[0] = src[4 * u2]; v4[1] = src[4 * u2 + 1];
      v4[2] = src[4 * u2 + 2]; v4[3] = src[4 * u2 + 3];
      *(ux4*)(dst + u2 * 8) = v4;
    }
  }
}

// ---------------- launch ----------------

extern "C" void kernel_launch(void* const* d_in, const int* in_sizes, int n_in,
                              void* d_out, int out_size, void* d_ws, size_t ws_size,
                              hipStream_t stream) {
  const float* x    = (const float*)d_in[0];
  const float* cosb = (const float*)d_in[1];
  const float* sinb = (const float*)d_in[2];
  const float* wq   = (const float*)d_in[3];
  const float* wk   = (const float*)d_in[4];
  const float* wv   = (const float*)d_in[5];
  const float* wo   = (const float*)d_in[6];
  float* out = (float*)d_out;

  char* ws = (char*)d_ws;
  unsigned short* xb    = (unsigned short*)ws;                 //  8,388,608 B
  unsigned short* attn  = (unsigned short*)ws;                 //  (alias; xb dead by then)
  unsigned short* wqkvT = (unsigned short*)(ws + 8388608);     //  3,145,728 B
  unsigned short* woT   = (unsigned short*)(ws + 11534336);    //  2,097,152 B
  unsigned short* qkv   = (unsigned short*)(ws + 13631488);    // 10,485,760 B (stride 1280)
  unsigned short* vT    = (unsigned short*)(ws + 24117248);    //  2,097,152 B (total 26.2 MiB)

  cvt_x_kernel<<<2048, 256, 0, stream>>>(x, xb);
  tw_kernel<<<dim3(40, 16), 256, 0, stream>>>(wq, wk, wv, wo, wqkvT, woT);
  gemm_bt_kernel<true, true><<<dim3(64, 12), 256, 0, stream>>>(xb, wqkvT, qkv, 1024, 1280, cosb, sinb, vT);
  attn_kernel<<<2048, 64, 0, stream>>>(qkv, vT, attn);
  gemm_bt_kernel<false, false><<<dim3(64, 8), 256, 0, stream>>>(attn, woT, out, 1024, 1024, nullptr, nullptr, nullptr);
}

// Round 8
// 183.798 us; speedup vs baseline: 1.1794x; 1.1080x over previous
//
#include <hip/hip_runtime.h>
#include <hip/hip_bf16.h>

// B=2, S=2048, HID=1024, H=16, KVH=4, D=64, G=4
// qkv row stride 1280 (q:0..1023, k:1024..1279); v goes straight to vT[b][kvh][64][2048]

typedef short bfx4 __attribute__((ext_vector_type(4)));
typedef short bfx8 __attribute__((ext_vector_type(8)));   // 8 bf16 (4 VGPRs)
typedef float fx4  __attribute__((ext_vector_type(4)));   // MFMA C/D 16x16
typedef float fx16 __attribute__((ext_vector_type(16)));  // MFMA C/D 32x32
typedef unsigned int ux4 __attribute__((ext_vector_type(4)));

#define DEV __device__ __forceinline__
#define ALPHA 0.18033688011112042f   // 1/sqrt(64) * log2(e), folded into q at GEMM1 epilogue

DEV void load_lds16(const void* g, void* l) {
  __builtin_amdgcn_global_load_lds(
      (const __attribute__((address_space(1))) unsigned int*)g,
      (__attribute__((address_space(3))) unsigned int*)l, 16, 0, 0);
}

DEV unsigned short f2bf(float f) {
  unsigned int x = __builtin_bit_cast(unsigned int, f);
  unsigned int r = (x + 0x7fffu + ((x >> 16) & 1u)) >> 16;
  return (unsigned short)r;
}
DEV float exp2_fast(float x) { float r; asm("v_exp_f32 %0, %1" : "=v"(r) : "v"(x)); return r; }
DEV unsigned cvtpk(float lo, float hi) {
  unsigned r; asm("v_cvt_pk_bf16_f32 %0, %1, %2" : "=v"(r) : "v"(lo), "v"(hi)); return r;
}
#define MFMA32 __builtin_amdgcn_mfma_f32_32x32x16_bf16

// ---------------- x fp32 -> bf16 ----------------

__global__ __launch_bounds__(256) void cvt_x_kernel(const float* __restrict__ x,
                                                    unsigned short* __restrict__ out) {
  int i = (blockIdx.x * 256 + threadIdx.x) * 8;
  fx4 a = *(const fx4*)(x + i);
  fx4 b = *(const fx4*)(x + i + 4);
  bfx8 r;
  r[0] = (short)f2bf(a[0]); r[1] = (short)f2bf(a[1]);
  r[2] = (short)f2bf(a[2]); r[3] = (short)f2bf(a[3]);
  r[4] = (short)f2bf(b[0]); r[5] = (short)f2bf(b[1]);
  r[6] = (short)f2bf(b[2]); r[7] = (short)f2bf(b[3]);
  *(bfx8*)(out + i) = r;
}

// ---------------- fused weight transposes (f32 -> bf16), LDS-tiled ----------------

__global__ __launch_bounds__(256) void tw_kernel(const float* __restrict__ wq,
                                                 const float* __restrict__ wk,
                                                 const float* __restrict__ wv,
                                                 const float* __restrict__ wo,
                                                 unsigned short* __restrict__ wqkvT,
                                                 unsigned short* __restrict__ woT) {
  __shared__ float tile[64 * 65];
  const int bx = blockIdx.x;
  const int c0 = blockIdx.y * 64;
  const float* src; int ncols, rofs, r0; unsigned short* dst;
  if (bx < 24) {
    r0 = bx * 64; dst = wqkvT;
    if (r0 < 1024)      { src = wq; ncols = 1024; rofs = r0; }
    else if (r0 < 1280) { src = wk; ncols = 256;  rofs = r0 - 1024; }
    else                { src = wv; ncols = 256;  rofs = r0 - 1280; }
  } else {
    r0 = (bx - 24) * 64; dst = woT; src = wo; ncols = 1024; rofs = r0;
  }
  const int t = threadIdx.x;
#pragma unroll
  for (int p = 0; p < 4; ++p) {
    int idx = p * 256 + t;
    int cc = idx >> 4, q4 = idx & 15;
    fx4 v = *(const fx4*)(src + (size_t)(c0 + cc) * ncols + rofs + q4 * 4);
#pragma unroll
    for (int i = 0; i < 4; ++i) tile[(q4 * 4 + i) * 65 + cc] = v[i];
  }
  __syncthreads();
#pragma unroll
  for (int p = 0; p < 2; ++p) {
    int idx = p * 256 + t;
    int rr = idx >> 3, c8 = idx & 7;
    bfx8 v8;
#pragma unroll
    for (int i = 0; i < 8; ++i) v8[i] = (short)f2bf(tile[rr * 65 + c8 * 8 + i]);
    *(bfx8*)(dst + (size_t)(r0 + rr) * 1024 + c0 + c8 * 8) = v8;
  }
}

// ---------------- GEMM 64x128 tile: C[M][ldc] = A[M][K] * Bt[N][K]^T ----------------
// 4 waves of 32x64; FUSE_ROPE: cols<1280 -> rope -> qkv (ld 1280); cols>=1280 -> vT (transposed).

template <bool OUT_BF16, bool FUSE_ROPE>
__global__ __launch_bounds__(256) void gemm_bt_kernel(const unsigned short* __restrict__ A,
                                                      const unsigned short* __restrict__ Bt,
                                                      void* __restrict__ Cp,
                                                      int K, int ldc,
                                                      const float* __restrict__ ct,
                                                      const float* __restrict__ st,
                                                      unsigned short* __restrict__ vTout) {
  __shared__ __align__(16) unsigned short As[64 * 32];
  __shared__ __align__(16) unsigned short Bs[128 * 32];
  const int t = threadIdx.x;
  const int l = t & 63;
  const int w = t >> 6;
  const int wm = (w >> 1) * 32, wn = (w & 1) * 64;
  const int bm = blockIdx.x, bn = blockIdx.y;
  fx4 acc[2][4] = {};

  for (int kt = 0; kt < K; kt += 32) {
    __syncthreads();
    {
      int rr = t >> 2, ca = t & 3;
      int gca = ((ca ^ ((rr >> 1) & 3)) * 8);
      load_lds16(A + (size_t)(bm * 64 + rr) * K + kt + gca, (char*)As + t * 16);
    }
#pragma unroll
    for (int p = 0; p < 2; ++p) {
      int idx = p * 256 + t;
      int rr = idx >> 2, ca = idx & 3;
      int gca = ((ca ^ ((rr >> 1) & 3)) * 8);
      load_lds16(Bt + (size_t)(bn * 128 + rr) * K + kt + gca, (char*)Bs + idx * 16);
    }
    __syncthreads();

    bfx8 af[2], bfr[4];
#pragma unroll
    for (int mi = 0; mi < 2; ++mi) {
      int row = wm + mi * 16 + (l & 15);
      int ch = (l >> 4) ^ ((row >> 1) & 3);
      af[mi] = *(const bfx8*)(As + row * 32 + ch * 8);
    }
#pragma unroll
    for (int ni = 0; ni < 4; ++ni) {
      int rowb = wn + ni * 16 + (l & 15);
      int chb = (l >> 4) ^ ((rowb >> 1) & 3);
      bfr[ni] = *(const bfx8*)(Bs + rowb * 32 + chb * 8);
    }
#pragma unroll
    for (int mi = 0; mi < 2; ++mi)
#pragma unroll
      for (int ni = 0; ni < 4; ++ni)
        acc[mi][ni] = __builtin_amdgcn_mfma_f32_16x16x32_bf16(af[mi], bfr[ni], acc[mi][ni], 0, 0, 0);
  }

  const int colbase = bn * 128 + wn;              // head-aligned 64-col window
  if (FUSE_ROPE && colbase < 1280) {
    const float qsc = (colbase < 1024) ? ALPHA : 1.0f;
    unsigned short* Cb = (unsigned short*)Cp;
#pragma unroll
    for (int mi = 0; mi < 2; ++mi) {
      int row0 = bm * 64 + wm + mi * 16 + (l >> 4) * 4;
#pragma unroll
      for (int r = 0; r < 4; ++r) {
        int row = row0 + r, s = row & 2047;
#pragma unroll
        for (int ni = 0; ni < 2; ++ni) {
          int d = ni * 16 + (l & 15);
          float c = ct[s * 64 + d], sn = st[s * 64 + d];
          float x0 = acc[mi][ni][r], x1 = acc[mi][ni + 2][r];
          Cb[(size_t)row * 1280 + colbase + d]      = f2bf((x0 * c - x1 * sn) * qsc);
          Cb[(size_t)row * 1280 + colbase + d + 32] = f2bf((x1 * c + x0 * sn) * qsc);
        }
      }
    }
  } else if (FUSE_ROPE) {
    // v-part: write transposed to vT[(b*4+kvh)*64 + d][s], 8B packs (4 consecutive s)
    const int b4 = (bm >> 5) * 4;                 // b = bm*64 / 2048
#pragma unroll
    for (int mi = 0; mi < 2; ++mi) {
      int row0 = bm * 64 + wm + mi * 16 + (l >> 4) * 4;
      int s0r = row0 & 2047;
#pragma unroll
      for (int ni = 0; ni < 4; ++ni) {
        int vcol = colbase + ni * 16 + (l & 15) - 1280;
        int kvh = vcol >> 6, d = vcol & 63;
        bfx4 pv;
#pragma unroll
        for (int r = 0; r < 4; ++r) pv[r] = (short)f2bf(acc[mi][ni][r]);
        *(bfx4*)(vTout + ((size_t)(b4 + kvh) * 64 + d) * 2048 + s0r) = pv;
      }
    }
  } else {
#pragma unroll
    for (int mi = 0; mi < 2; ++mi) {
      int row0 = bm * 64 + wm + mi * 16 + (l >> 4) * 4;
#pragma unroll
      for (int ni = 0; ni < 4; ++ni) {
        int col = colbase + ni * 16 + (l & 15);
#pragma unroll
        for (int r = 0; r < 4; ++r) {
          if (OUT_BF16)
            ((unsigned short*)Cp)[(size_t)(row0 + r) * ldc + col] = f2bf(acc[mi][ni][r]);
          else
            ((float*)Cp)[(size_t)(row0 + r) * ldc + col] = acc[mi][ni][r];
        }
      }
    }
  }
}

// ---------------- flash attention v8: 4 waves share coalesced LDS K/V staging ----------------
// 512 blocks x 256 thr. Block group g=bx>>5 -> T = g<8 ? 15-g : g-8 (paired blocks sum to
// uniform 36 steps/CU); hb = bx&31 -> (head,b). Wave w owns q-tile 4T+w (32 rows,
// q0 = T*128 + 32w). KV steps of 64 keys, nkb = 2T+2; wave skips steps past its diagonal
// (kbd = 2T + (w>>1)) but keeps barriers. K tile [key][d] and V^T tile [d][s] both staged
// 128B/row via global_load_lds with chunk-XOR swizzle (pre-swizzled global source, rule 21).
// Swapped QK^T + swapped PV (round-7 verified STEP internals).

__global__ __launch_bounds__(256, 2) void attn_kernel(const unsigned short* __restrict__ qkv,
                                                      const unsigned short* __restrict__ vT,
                                                      unsigned short* __restrict__ out) {
  __shared__ __align__(16) unsigned short Kl[2][64 * 64];   // 8 KB each
  __shared__ __align__(16) unsigned short Vl[2][64 * 64];   // 8 KB each
  __shared__ unsigned Ost[4][32 * 33];                      // per-wave transpose buffer

  const int bx = blockIdx.x;
  const int g = bx >> 5;
  const int T = (g < 8) ? (15 - g) : (g - 8);
  const int hb = bx & 31;
  const int head = hb & 15, b = hb >> 4;
  const int kvh = head >> 2;
  const int t = threadIdx.x, w = t >> 6, l = t & 63;
  const int q5 = l & 31, h = l >> 5;
  const int q0 = T * 128 + w * 32;
  const int nkb = 2 * T + 2;
  const int kbd = 2 * T + (w >> 1);          // diagonal step for this wave
  const size_t bbase = (size_t)b * 2048;
  const unsigned short* base = qkv + bbase * 1280;
  const unsigned short* kbase = base + 1024 + kvh * 64;
  const unsigned short* vbase = vT + (size_t)(b * 4 + kvh) * 64 * 2048;

  bfx8 qf[4];
#pragma unroll
  for (int dd = 0; dd < 4; ++dd)
    qf[dd] = *(const bfx8*)(base + (size_t)(q0 + q5) * 1280 + head * 64 + dd * 16 + 8 * h);

  fx16 o[2] = {};
  float mrun = -1e30f, lrun = 0.f;

#define STAGE(NXT, KBN) do {                                                     \
    const int j0n = (KBN) * 64;                                                  \
    _Pragma("unroll")                                                            \
    for (int p = 0; p < 2; ++p) {                                                \
      int idx = p * 256 + t, j = idx >> 3, c = idx & 7;                          \
      int gc = (c ^ (j & 7)) * 8;                                                \
      load_lds16(kbase + (size_t)(j0n + j) * 1280 + gc,                          \
                 (char*)&Kl[NXT][0] + idx * 16);                                 \
    }                                                                            \
    _Pragma("unroll")                                                            \
    for (int p = 0; p < 2; ++p) {                                                \
      int idx = p * 256 + t, j = idx >> 3, c = idx & 7;                          \
      int gc = (c ^ (j & 7)) * 8;                                                \
      load_lds16(vbase + (size_t)j * 2048 + j0n + gc,                            \
                 (char*)&Vl[NXT][0] + idx * 16);                                 \
    }                                                                            \
  } while (0)

#define STEP(CUR, KB) do {                                                       \
    const char* Kb = (const char*)&Kl[CUR][0];                                   \
    const char* Vb = (const char*)&Vl[CUR][0];                                   \
    bfx8 kf0[4], kf1[4];                                                         \
    _Pragma("unroll")                                                            \
    for (int dd = 0; dd < 4; ++dd) {                                             \
      int slot = ((2 * dd + h) ^ (q5 & 7)) * 16;                                 \
      kf0[dd] = *(const bfx8*)(Kb + q5 * 128 + slot);                            \
      kf1[dd] = *(const bfx8*)(Kb + (32 + q5) * 128 + slot);                     \
    }                                                                            \
    fx16 s0 = {}, s1 = {};                                                       \
    __builtin_amdgcn_s_setprio(1);                                               \
    s0 = MFMA32(kf0[0], qf[0], s0, 0, 0, 0);                                     \
    s1 = MFMA32(kf1[0], qf[0], s1, 0, 0, 0);                                     \
    s0 = MFMA32(kf0[1], qf[1], s0, 0, 0, 0);                                     \
    s1 = MFMA32(kf1[1], qf[1], s1, 0, 0, 0);                                     \
    s0 = MFMA32(kf0[2], qf[2], s0, 0, 0, 0);                                     \
    s1 = MFMA32(kf1[2], qf[2], s1, 0, 0, 0);                                     \
    s0 = MFMA32(kf0[3], qf[3], s0, 0, 0, 0);                                     \
    s1 = MFMA32(kf1[3], qf[3], s1, 0, 0, 0);                                     \
    __builtin_amdgcn_s_setprio(0);                                               \
    if ((KB) == kbd) {                                                           \
      const int j0s = (KB) * 64;                                                 \
      _Pragma("unroll")                                                          \
      for (int r = 0; r < 16; ++r) {                                             \
        int key0 = j0s + (r & 3) + 8 * (r >> 2) + 4 * h;                         \
        if (key0 > q0 + q5) s0[r] = -1e30f;                                      \
        if (key0 + 32 > q0 + q5) s1[r] = -1e30f;                                 \
      }                                                                          \
    }                                                                            \
    float pmax = fmaxf(s0[0], s1[0]);                                            \
    _Pragma("unroll")                                                            \
    for (int r = 1; r < 16; ++r) pmax = fmaxf(pmax, fmaxf(s0[r], s1[r]));        \
    pmax = fmaxf(pmax, __shfl_xor(pmax, 32, 64));                                \
    if (!__all(pmax <= mrun + 8.0f)) {                                           \
      float mnew = fmaxf(mrun, pmax);                                            \
      float corr = exp2_fast(mrun - mnew);                                       \
      mrun = mnew;                                                               \
      lrun *= corr;                                                              \
      o[0] *= corr; o[1] *= corr;                                                \
    }                                                                            \
    float lt0 = 0.f, lt1 = 0.f;                                                  \
    _Pragma("unroll")                                                            \
    for (int r = 0; r < 16; ++r) {                                               \
      float p0 = exp2_fast(s0[r] - mrun); s0[r] = p0; lt0 += p0;                 \
      float p1 = exp2_fast(s1[r] - mrun); s1[r] = p1; lt1 += p1;                 \
    }                                                                            \
    float lt = lt0 + lt1;                                                        \
    lt += __shfl_xor(lt, 32, 64);                                                \
    lrun += lt;                                                                  \
    unsigned U[2][8];                                                            \
    _Pragma("unroll")                                                            \
    for (int k8 = 0; k8 < 8; ++k8) {                                             \
      U[0][k8] = cvtpk(s0[2 * k8], s0[2 * k8 + 1]);                              \
      U[1][k8] = cvtpk(s1[2 * k8], s1[2 * k8 + 1]);                              \
    }                                                                            \
    _Pragma("unroll")                                                            \
    for (int hs = 0; hs < 2; ++hs) {                                             \
      _Pragma("unroll")                                                          \
      for (int e = 0; e < 2; ++e) {                                              \
        unsigned send0 = h ? U[hs][4 * e] : U[hs][4 * e + 2];                    \
        unsigned send1 = h ? U[hs][4 * e + 1] : U[hs][4 * e + 3];                \
        unsigned r0 = (unsigned)__shfl_xor((int)send0, 32, 64);                  \
        unsigned r1 = (unsigned)__shfl_xor((int)send1, 32, 64);                  \
        unsigned k0 = h ? U[hs][4 * e + 2] : U[hs][4 * e];                       \
        unsigned k1 = h ? U[hs][4 * e + 3] : U[hs][4 * e + 1];                   \
        ux4 fr;                                                                  \
        fr[0] = h ? r0 : k0; fr[1] = h ? r1 : k1;                                \
        fr[2] = h ? k0 : r0; fr[3] = h ? k1 : r1;                                \
        bfx8 pf = __builtin_bit_cast(bfx8, fr);                                  \
        int ks = 2 * hs + e;                                                     \
        int vslot = ((2 * ks + h) ^ (q5 & 7)) * 16;                              \
        bfx8 vf0 = *(const bfx8*)(Vb + q5 * 128 + vslot);                        \
        bfx8 vf1 = *(const bfx8*)(Vb + (32 + q5) * 128 + vslot);                 \
        __builtin_amdgcn_s_setprio(1);                                           \
        o[0] = MFMA32(vf0, pf, o[0], 0, 0, 0);                                   \
        o[1] = MFMA32(vf1, pf, o[1], 0, 0, 0);                                   \
        __builtin_amdgcn_s_setprio(0);                                           \
      }                                                                          \
    }                                                                            \
  } while (0)

  STAGE(0, 0);
  __syncthreads();
#pragma unroll 1
  for (int kb = 0; kb < nkb; ++kb) {
    const int cur = kb & 1;
    if (kb + 1 < nkb) STAGE(cur ^ 1, kb + 1);
    if (kb <= kbd) STEP(cur, kb);
    __syncthreads();
  }
#undef STAGE
#undef STEP

  // ---- epilogue: O^T -> per-wave LDS transpose -> coalesced bf16 store ----
  float inv = 1.0f / lrun;
  unsigned* OstW = &Ost[w][0];
#pragma unroll
  for (int dt = 0; dt < 2; ++dt)
#pragma unroll
    for (int rp = 0; rp < 8; ++rp) {
      int r = 2 * rp;
      int d = 32 * dt + (r & 3) + 8 * (r >> 2) + 4 * h;   // even d; pair (d, d+1)
      OstW[q5 * 33 + (d >> 1)] = cvtpk(o[dt][r] * inv, o[dt][r + 1] * inv);
    }
  asm volatile("s_waitcnt lgkmcnt(0)" ::: "memory");
  __builtin_amdgcn_sched_barrier(0);
  {
    int rr = l >> 1, half = l & 1;
    const unsigned* src = OstW + rr * 33 + half * 16;
    unsigned short* dst = out + (bbase + q0 + rr) * 1024 + head * 64 + half * 32;
#pragma unroll
    for (int u2 = 0; u2 < 4; ++u2) {
      ux4 v4;
      v4[0] = src[4 * u2]; v4[1] = src[4 * u2 + 1];
      v4[2] = src[4 * u2 + 2]; v4[3] = src[4 * u2 + 3];
      *(ux4*)(dst + u2 * 8) = v4;
    }
  }
}

// ---------------- launch ----------------

extern "C" void kernel_launch(void* const* d_in, const int* in_sizes, int n_in,
                              void* d_out, int out_size, void* d_ws, size_t ws_size,
                              hipStream_t stream) {
  const float* x    = (const float*)d_in[0];
  const float* cosb = (const float*)d_in[1];
  const float* sinb = (const float*)d_in[2];
  const float* wq   = (const float*)d_in[3];
  const float* wk   = (const float*)d_in[4];
  const float* wv   = (const float*)d_in[5];
  const float* wo   = (const float*)d_in[6];
  float* out = (float*)d_out;

  char* ws = (char*)d_ws;
  unsigned short* xb    = (unsigned short*)ws;                 //  8,388,608 B
  unsigned short* attn  = (unsigned short*)ws;                 //  (alias; xb dead by then)
  unsigned short* wqkvT = (unsigned short*)(ws + 8388608);     //  3,145,728 B
  unsigned short* woT   = (unsigned short*)(ws + 11534336);    //  2,097,152 B
  unsigned short* qkv   = (unsigned short*)(ws + 13631488);    // 10,485,760 B (stride 1280)
  unsigned short* vT    = (unsigned short*)(ws + 24117248);    //  2,097,152 B (total 26.2 MiB)

  cvt_x_kernel<<<2048, 256, 0, stream>>>(x, xb);
  tw_kernel<<<dim3(40, 16), 256, 0, stream>>>(wq, wk, wv, wo, wqkvT, woT);
  gemm_bt_kernel<true, true><<<dim3(64, 12), 256, 0, stream>>>(xb, wqkvT, qkv, 1024, 1280, cosb, sinb, vT);
  attn_kernel<<<512, 256, 0, stream>>>(qkv, vT, attn);
  gemm_bt_kernel<false, false><<<dim3(64, 8), 256, 0, stream>>>(attn, woT, out, 1024, 1024, nullptr, nullptr, nullptr);
}